// Round 10
// baseline (67.853 us; speedup 1.0000x reference)
//
#include <hip/hip_runtime.h>

// Laplacian pyramid loss via linearity: pyr(p) - pyr(t) = pyr(p - t).
// R10: R9's async-LDS ring streaming, restructured for wave residency.
// R9 had 1 wave / 64-thread block, 32KB LDS -> 2-3 waves/CU (Occupancy 6.8%,
// VALU 8.9%): every vmcnt wait idled the SIMD. Now: 4 independent wave-bands
// per 256-thread block, ring shrunk to 4 slots (L0 16KB/wave = 64KB/block ->
// 2 blocks/CU = 8 waves/CU). Ring discipline (NRING=4):
//   end of iter j stages rows (2j+7, 2j+8)  [2 ahead]
//   iter j reads win rows (2j+3, 2j+4); live set = 4 distinct slots
//   lap cur rows extracted from the SAME window reads into registers
//   (cEv pipeline depth 2, cOd depth 1) -- no separate read_cur ds_reads.
// vmcnt is in-order on CDNA: wait N = (#ops issued after the needed pair)
// incl. the 1 store/iter: L0 exact 9 -> use 8; L1/L2 exact 3 -> use 2.
// lgkmcnt(0) fence before each stage pair: ds_reads retired before the DMA
// write to the reused slot can be issued. Compute algebra unchanged (R7-R9
// validated): h 5-tap, rolling v-tap, rolling ex/ox up-interp, lane-local
// edge-reflect selects. Tail (L3+L4) + finish unchanged.

__device__ __forceinline__ int reflect_i(int m, int S) {
    if (m < 0) m = -m;
    if (m >= S) m = 2 * S - 2 - m;
    return m;
}

__device__ __forceinline__ void wg_barrier() {
    asm volatile("s_waitcnt lgkmcnt(0)" ::: "memory");
    __builtin_amdgcn_s_barrier();
}

#define LGKM0 asm volatile("s_waitcnt lgkmcnt(0)" ::: "memory")

template <int N>
__device__ __forceinline__ void wait_vm() {
    if constexpr (N == 0)      asm volatile("s_waitcnt vmcnt(0)" ::: "memory");
    else if constexpr (N == 1) asm volatile("s_waitcnt vmcnt(1)" ::: "memory");
    else if constexpr (N == 2) asm volatile("s_waitcnt vmcnt(2)" ::: "memory");
    else if constexpr (N == 4) asm volatile("s_waitcnt vmcnt(4)" ::: "memory");
    else if constexpr (N == 8) asm volatile("s_waitcnt vmcnt(8)" ::: "memory");
}

__device__ __forceinline__ void gld16(const void* g, void* l) {
    __builtin_amdgcn_global_load_lds(
        (const __attribute__((address_space(1))) void*)g,
        (__attribute__((address_space(3))) void*)l, 16, 0, 0);
}

// XOR-swizzle within a 2KB row slot (involution, 16B units) — breaks the
// 32B-lane-stride b128 bank aliasing for CPL=4. Validated R9 (absmax 0).
__device__ __forceinline__ int swz4(int B) { return B ^ (((B >> 7) & 7) << 4); }

template <int S, int ISL0, int DH>
__global__ __launch_bounds__(256, 2)
void pyr_kernel(const float* __restrict__ a, const float* __restrict__ b,
                float* __restrict__ dwn, float* __restrict__ acc, float scale) {
    constexpr int D = S / 2;
    constexpr int CPL = S / 128;                  // down cols per lane: 4/2/1
    constexpr int W = 2 * CPL + 3;                // cur window floats per lane
    constexpr int ROWB = (CPL == 4) ? 2048 : 1024;
    constexpr int SLOT = ROWB * (ISL0 ? 2 : 1);   // a (+ b) per ring slot
    constexpr int OPS = (CPL == 4) ? (ISL0 ? 4 : 2) : 1;  // gld16 per stage_row
    constexpr int NRS = D / DH;

    __shared__ float4 ringmem[4 * 4 * SLOT / 16]; // 4 waves x 4 slots
    const int wv = threadIdx.x >> 6;
    const int lane = threadIdx.x & 63;
    char* ring = (char*)ringmem + wv * (4 * SLOT);

    const int wid = blockIdx.x * 4 + wv;
    const int rs = wid % NRS;
    const int n = wid / NRS;
    const int R0 = rs * DH;
    const size_t gbase = (size_t)n * S * S;

    auto stage_row = [&](int s) {
        int gr = reflect_i(2 * R0 - 4 + s, S);
        const char* ga = (const char*)(a + gbase + (size_t)gr * S);
        char* la = ring + (s & 3) * SLOT;
        if constexpr (CPL == 4) {
            gld16(ga + swz4(16 * lane), la);
            gld16(ga + swz4(16 * lane + 1024), la + 1024);
        } else if constexpr (CPL == 2) {
            gld16(ga + 16 * lane, la);
        } else {
            gld16(ga + 16 * (lane & 31), la);    // 512B row; lanes>=32 -> pad
        }
        if constexpr (ISL0) {
            const char* gb = (const char*)(b + gbase + (size_t)gr * S);
            gld16(gb + swz4(16 * lane), la + ROWB);
            gld16(gb + swz4(16 * lane + 1024), la + ROWB + 1024);
        }
    };

    // 5-tap cur window (cols 2*CPL*lane-2 .. +2*CPL) for row seq s.
    // w[2..W-2] are the lane's own cur cols (already p-t for L0).
    auto read_win = [&](int s, float* w) {
        const char* pa = ring + (s & 3) * SLOT;
        if constexpr (CPL == 4) {
            int bl = 32 * lane;
            float2 lo = *(const float2*)(pa + swz4(lane ? bl - 8 : 0));
            float4 m0 = *(const float4*)(pa + swz4(bl));
            float4 m1 = *(const float4*)(pa + swz4(bl + 16));
            float hi = *(const float*)(pa + swz4(lane == 63 ? 2032 : bl + 32));
            w[0]=lo.x; w[1]=lo.y; w[2]=m0.x; w[3]=m0.y; w[4]=m0.z; w[5]=m0.w;
            w[6]=m1.x; w[7]=m1.y; w[8]=m1.z; w[9]=m1.w; w[10]=hi;
            if constexpr (ISL0) {
                const char* pb = pa + ROWB;
                float2 l2 = *(const float2*)(pb + swz4(lane ? bl - 8 : 0));
                float4 t0 = *(const float4*)(pb + swz4(bl));
                float4 t1 = *(const float4*)(pb + swz4(bl + 16));
                float h2 = *(const float*)(pb + swz4(lane == 63 ? 2032 : bl + 32));
                w[0]-=l2.x; w[1]-=l2.y; w[2]-=t0.x; w[3]-=t0.y; w[4]-=t0.z;
                w[5]-=t0.w; w[6]-=t1.x; w[7]-=t1.y; w[8]-=t1.z; w[9]-=t1.w; w[10]-=h2;
            }
        } else if constexpr (CPL == 2) {
            int bl = 16 * lane;
            float2 lo = *(const float2*)(pa + (lane ? bl - 8 : 0));
            float4 m0 = *(const float4*)(pa + bl);
            float hi = *(const float*)(pa + (lane == 63 ? 1008 : bl + 16));
            w[0]=lo.x; w[1]=lo.y; w[2]=m0.x; w[3]=m0.y; w[4]=m0.z; w[5]=m0.w; w[6]=hi;
        } else {
            int bl = 8 * lane;
            float2 lo = *(const float2*)(pa + (lane ? bl - 8 : 0));
            float2 m0 = *(const float2*)(pa + bl);
            float hi = *(const float*)(pa + (lane == 63 ? 496 : bl + 8));
            w[0]=lo.x; w[1]=lo.y; w[2]=m0.x; w[3]=m0.y; w[4]=hi;
        }
        // image-edge reflect (full-width wave: lane0/lane63 are the edges)
        if (lane == 0)  { w[0] = w[4]; w[1] = w[3]; }
        if (lane == 63) { w[W - 1] = w[W - 3]; }
    };

    auto hof = [&](const float* w, float* h) {
        #pragma unroll
        for (int j = 0; j < CPL; j++)
            h[j] = w[2*j] + 4.f*w[2*j+1] + 6.f*w[2*j+2] + 4.f*w[2*j+3] + w[2*j+4];
    };

    float hA[CPL], hB[CPL], hC[CPL], hD[CPL], hE[CPL];
    float cEv1[2*CPL], cEv2[2*CPL], cOd1[2*CPL];
    float ex0[CPL] = {}, ex1[CPL] = {}, ox0[CPL] = {}, ox1[CPL] = {};
    float sum = 0.f;
    float* dbase = dwn + (size_t)n * D * D;

    // prologue: fill 4 slots, read rows 0-2, refill freed slots with 4-6
    stage_row(0); stage_row(1); stage_row(2); stage_row(3);
    wait_vm<OPS>();                       // rows 0-2 landed (row 3 may fly)
    {
        float w[W];
        read_win(0, w); hof(w, hA);
        read_win(1, w); hof(w, hB);
        read_win(2, w); hof(w, hC);
    }
    LGKM0;
    stage_row(4); stage_row(5); stage_row(6);

    #pragma unroll
    for (int j = 0; j <= DH + 1; ++j) {
        const int m = R0 - 1 + j;
        if (j <= DH) wait_vm<2 * OPS>(); else wait_vm<0>();

        float w3[W], w4[W];
        read_win(2 * j + 3, w3); hof(w3, hD);
        read_win(2 * j + 4, w4); hof(w4, hE);

        float d[CPL], dl[CPL], dr[CPL], ex2[CPL], ox2[CPL];
        #pragma unroll
        for (int q = 0; q < CPL; q++)
            d[q] = (hA[q] + 4.f*hB[q] + 6.f*hC[q] + 4.f*hD[q] + hE[q]) * (1.f / 256.f);
        float dli = __shfl_up(d[CPL - 1], 1, 64);
        float dri = __shfl_down(d[0], 1, 64);
        dl[0] = (lane == 0) ? ((CPL > 1) ? d[1] : dri) : dli;   // col -1 -> 1
        #pragma unroll
        for (int q = 1; q < CPL; q++) dl[q] = d[q - 1];
        dr[CPL - 1] = (lane == 63) ? d[CPL - 1] : dri;          // col D -> D-1
        #pragma unroll
        for (int q = 0; q < CPL - 1; q++) dr[q] = d[q + 1];
        #pragma unroll
        for (int q = 0; q < CPL; q++) {
            ex2[q] = 0.125f * (dl[q] + 6.f * d[q] + dr[q]);
            ox2[q] = 0.5f * (d[q] + dr[q]);
        }

        if (j >= 1 && j <= DH) {
            char* dst = (char*)(dbase + (size_t)m * D + CPL * lane);
            if constexpr (CPL == 4)      *(float4*)dst = make_float4(d[0], d[1], d[2], d[3]);
            else if constexpr (CPL == 2) *(float2*)dst = make_float2(d[0], d[1]);
            else                         *(float*)dst = d[0];
        }

        if (j >= 2) {
            const int me = m - 1;
            #pragma unroll
            for (int q = 0; q < CPL; q++) {
                float eA = (me == 0) ? ex2[q] : ex0[q];       // down row -1 -> 1
                float oA = (me == 0) ? ox2[q] : ox0[q];
                float eC = (me == D - 1) ? ex1[q] : ex2[q];   // down row D -> D-1
                float oC = (me == D - 1) ? ox1[q] : ox2[q];
                float uee = 0.125f * (eA + 6.f * ex1[q] + eC);
                float ueo = 0.125f * (oA + 6.f * ox1[q] + oC);
                float uoe = 0.5f * (ex1[q] + eC);
                float uoo = 0.5f * (ox1[q] + oC);
                sum += fabsf(cEv2[2*q]   - uee) + fabsf(cEv2[2*q+1] - ueo)
                     + fabsf(cOd1[2*q]   - uoe) + fabsf(cOd1[2*q+1] - uoo);
            }
        }

        #pragma unroll
        for (int q = 0; q < CPL; q++) {
            ex0[q] = ex1[q]; ex1[q] = ex2[q];
            ox0[q] = ox1[q]; ox1[q] = ox2[q];
            hA[q] = hC[q]; hB[q] = hD[q]; hC[q] = hE[q];
        }
        #pragma unroll
        for (int q = 0; q < 2 * CPL; q++) {
            cEv2[q] = cEv1[q];          // read @j-2: cur seq 2j   (even row)
            cEv1[q] = w4[2 + q];        // cur seq 2j+4 -> lap @j+2
            cOd1[q] = w3[2 + q];        // cur seq 2j+3 -> lap @j+1
        }

        if (j <= DH - 1) {
            LGKM0;                      // ds_reads retired before slot reuse
            stage_row(2 * j + 7);
            stage_row(2 * j + 8);
        }
    }

    #pragma unroll
    for (int o = 32; o > 0; o >>= 1) sum += __shfl_down(sum, o, 64);
    if (lane == 0) atomicAdd(&acc[wid & 63], sum * scale);
}

// ---- tail: levels 3+4 per image in LDS (proven R8/R9) ----
__device__ float level_in_lds(const float* cur, float* h, float* dn,
                              int S, int tid, int nt) {
    const int D = S >> 1;
    for (int i = tid; i < S * D; i += nt) {
        int r = i / D, xh = i % D;
        int c0 = reflect_i(2 * xh - 2, S), c1 = reflect_i(2 * xh - 1, S);
        int c3 = 2 * xh + 1, c4 = reflect_i(2 * xh + 2, S);
        const float* row = cur + r * S;
        h[i] = row[c0] + 4.f * row[c1] + 6.f * row[2 * xh] + 4.f * row[c3] + row[c4];
    }
    wg_barrier();
    for (int i = tid; i < D * D; i += nt) {
        int yh = i / D, xh = i % D;
        int r0 = reflect_i(2 * yh - 2, S), r1 = reflect_i(2 * yh - 1, S);
        int r3 = 2 * yh + 1, r4 = reflect_i(2 * yh + 2, S);
        dn[i] = (h[r0 * D + xh] + 4.f * h[r1 * D + xh] + 6.f * h[2 * yh * D + xh]
               + 4.f * h[r3 * D + xh] + h[r4 * D + xh]) * (1.f / 256.f);
    }
    wg_barrier();
    float sum = 0.f;
    for (int i = tid; i < D * D; i += nt) {
        int yh2 = i / D, q = i % D;
        int rm = (yh2 == 0) ? 1 : yh2 - 1;
        int rp = (yh2 == D - 1) ? D - 1 : yh2 + 1;
        int cm = (q == 0) ? 1 : q - 1;
        int cp = (q == D - 1) ? D - 1 : q + 1;
        float A00 = dn[rm * D + cm], A01 = dn[rm * D + q], A02 = dn[rm * D + cp];
        float A10 = dn[yh2 * D + cm], A11 = dn[yh2 * D + q], A12 = dn[yh2 * D + cp];
        float A20 = dn[rp * D + cm], A21 = dn[rp * D + q], A22 = dn[rp * D + cp];
        float ex0 = (A00 + 6.f * A01 + A02) * 0.125f;
        float ex1 = (A10 + 6.f * A11 + A12) * 0.125f;
        float ex2 = (A20 + 6.f * A21 + A22) * 0.125f;
        float ox0 = (A01 + A02) * 0.5f;
        float ox1 = (A11 + A12) * 0.5f;
        float ox2 = (A21 + A22) * 0.5f;
        float uee = (ex0 + 6.f * ex1 + ex2) * 0.125f;
        float ueo = (ox0 + 6.f * ox1 + ox2) * 0.125f;
        float uoe = (ex1 + ex2) * 0.5f;
        float uoo = (ox1 + ox2) * 0.5f;
        const float* c0 = cur + (2 * yh2) * S + 2 * q;
        sum += fabsf(c0[0] - uee) + fabsf(c0[1] - ueo)
             + fabsf(c0[S] - uoe) + fabsf(c0[S + 1] - uoo);
    }
    wg_barrier();
    return sum;
}

__global__ __launch_bounds__(256)
void tail_kernel(const float* __restrict__ d2, float* __restrict__ acc,
                 float s3, float s4) {
    __shared__ float cur[64 * 64];
    __shared__ float hbuf[64 * 32];
    __shared__ float dn3[32 * 32];
    __shared__ float dn4[16 * 16];
    int n = blockIdx.x, tid = threadIdx.x;
    const float4* src = (const float4*)(d2 + (size_t)n * 64 * 64);
    for (int i = tid; i < 64 * 16; i += 256) ((float4*)cur)[i] = src[i];
    wg_barrier();
    float sum = level_in_lds(cur, hbuf, dn3, 64, tid, 256) * s3;
    sum += level_in_lds(dn3, hbuf, dn4, 32, tid, 256) * s4;
    #pragma unroll
    for (int o = 32; o > 0; o >>= 1) sum += __shfl_down(sum, o, 64);
    __shared__ float s[4];
    int lane = tid & 63, w = tid >> 6;
    if (lane == 0) s[w] = sum;
    wg_barrier();
    if (tid == 0) atomicAdd(&acc[n & 63], s[0] + s[1] + s[2] + s[3]);
}

__global__ void finish_kernel(const float* __restrict__ acc, float* __restrict__ out) {
    float v = acc[threadIdx.x];
    #pragma unroll
    for (int o = 32; o > 0; o >>= 1) v += __shfl_down(v, o, 64);
    if (threadIdx.x == 0) out[0] = v;
}

extern "C" void kernel_launch(void* const* d_in, const int* in_sizes, int n_in,
                              void* d_out, int out_size, void* d_ws, size_t ws_size,
                              hipStream_t stream) {
    const float* p = (const float*)d_in[0];
    const float* t = (const float*)d_in[1];
    float* out = (float*)d_out;
    float* acc = (float*)d_ws;                    // 64 accumulator slots
    float* dn0 = acc + 64;                        // 48 * 256 * 256
    float* dn1 = dn0 + (size_t)48 * 256 * 256;    // 48 * 128 * 128
    float* dn2 = dn1 + (size_t)48 * 128 * 128;    // 48 * 64 * 64

    hipMemsetAsync(acc, 0, 64 * sizeof(float), stream);

    const int N = 48;  // 16 batch * 3 channels (depthwise)

    // L0: D=256, DH=8 -> 32 bands/img, 1536 waves in 384 blocks (4 waves ea)
    pyr_kernel<512, 1, 8><<<384, 256, 0, stream>>>(
        p, t, dn0, acc, 1.f / (float)(N * 512 * 512));
    // L1: D=128, DH=4 -> 32 bands/img, 1536 waves in 384 blocks
    pyr_kernel<256, 0, 4><<<384, 256, 0, stream>>>(
        dn0, nullptr, dn1, acc, 2.f / (float)(N * 256 * 256));
    // L2: D=64, DH=4 -> 16 bands/img, 768 waves in 192 blocks
    pyr_kernel<128, 0, 4><<<192, 256, 0, stream>>>(
        dn1, nullptr, dn2, acc, 4.f / (float)(N * 128 * 128));
    // L3+L4: one block per image, LDS-resident
    tail_kernel<<<N, 256, 0, stream>>>(dn2, acc,
                                       8.f / (float)(N * 64 * 64),
                                       16.f / (float)(N * 32 * 32));
    finish_kernel<<<1, 64, 0, stream>>>(acc, out);
}

// Round 11
// 66.261 us; speedup vs baseline: 1.0240x; 1.0240x over previous
//
#include <hip/hip_runtime.h>

// Laplacian pyramid loss via linearity: pyr(p) - pyr(t) = pyr(p - t).
// R11: R10's async-LDS ring (4 slots, stage-2-ahead, counted vmcnt, lgkm
// fence before slot reuse — discipline validated absmax=0 twice) with the
// read path rebuilt: LINEAR global_load_lds (no per-lane swizzle: R9/R10's
// pre-swizzled DMA source made every stage a scattered TA gather — the
// suspected ~10Kcy/iter serializer) + lane-owns-own-16B-chunk LDS layout:
//   L0 (S=512): lane l owns chunks l and 64+l -> two 2-down-col strips
//   L1 (S=256): lane l owns chunk l           -> 2 down cols
//   L2 (S=128): lane l owns 8B at 8l          -> 1 down col
// ds_read_b128/b64 at own chunk = conflict-free; 5-tap halos via 2-3
// __shfl per row (R7/R8-verified edge algebra: left 6c0+8c1+2c2, right
// +7cx, cross-half broadcasts). Compute: rolling v-tap, rolling ex/ox
// up-interp, lap-cur register pipeline (cEv depth 2 / cOd depth 1).
// Tail (L3+L4 per-image LDS pyramid) + finish unchanged.

__device__ __forceinline__ int reflect_i(int m, int S) {
    if (m < 0) m = -m;
    if (m >= S) m = 2 * S - 2 - m;
    return m;
}

__device__ __forceinline__ void wg_barrier() {
    asm volatile("s_waitcnt lgkmcnt(0)" ::: "memory");
    __builtin_amdgcn_s_barrier();
}

#define LGKM0 asm volatile("s_waitcnt lgkmcnt(0)" ::: "memory")

template <int N>
__device__ __forceinline__ void wait_vm() {
    if constexpr (N == 0)      asm volatile("s_waitcnt vmcnt(0)" ::: "memory");
    else if constexpr (N == 1) asm volatile("s_waitcnt vmcnt(1)" ::: "memory");
    else if constexpr (N == 2) asm volatile("s_waitcnt vmcnt(2)" ::: "memory");
    else if constexpr (N == 4) asm volatile("s_waitcnt vmcnt(4)" ::: "memory");
    else if constexpr (N == 8) asm volatile("s_waitcnt vmcnt(8)" ::: "memory");
}

__device__ __forceinline__ void gld16(const void* g, void* l) {
    __builtin_amdgcn_global_load_lds(
        (const __attribute__((address_space(1))) void*)g,
        (__attribute__((address_space(3))) void*)l, 16, 0, 0);
}

template <int S, int ISL0, int DH>
__global__ __launch_bounds__(256, 2)
void pyr_kernel(const float* __restrict__ a, const float* __restrict__ b,
                float* __restrict__ dwn, float* __restrict__ acc, float scale) {
    constexpr int D = S / 2;
    constexpr int CPL = S / 128;                  // down cols per lane: 4/2/1
    constexpr int ROWB = (CPL == 4) ? 2048 : 1024;
    constexpr int SLOT = ROWB * (ISL0 ? 2 : 1);
    constexpr int OPS = (CPL == 4) ? (ISL0 ? 4 : 2) : 1;  // gld16 per stage_row
    constexpr int NRS = D / DH;

    __shared__ float4 ringmem[4 * 4 * SLOT / 16]; // 4 waves x 4 slots
    const int wv = threadIdx.x >> 6;
    const int lane = threadIdx.x & 63;
    char* ring = (char*)ringmem + wv * (4 * SLOT);

    const int wid = blockIdx.x * 4 + wv;
    const int rs = wid % NRS;
    const int n = wid / NRS;
    const int R0 = rs * DH;
    const size_t gbase = (size_t)n * S * S;

    auto stage_row = [&](int s) {
        int gr = reflect_i(2 * R0 - 4 + s, S);
        const char* ga = (const char*)(a + gbase + (size_t)gr * S);
        char* la = ring + (s & 3) * SLOT;
        if constexpr (CPL == 4) {
            gld16(ga + 16 * lane, la);
            gld16(ga + 16 * lane + 1024, la + 1024);
        } else if constexpr (CPL == 2) {
            gld16(ga + 16 * lane, la);
        } else {
            gld16(ga + 16 * (lane & 31), la);    // 512B row; lanes>=32 dup pad
        }
        if constexpr (ISL0) {
            const char* gb = (const char*)(b + gbase + (size_t)gr * S);
            gld16(gb + 16 * lane, la + ROWB);
            gld16(gb + 16 * lane + 1024, la + ROWB + 1024);
        }
    };

    // own-chunk reads + shuffle halos; fills c[2*CPL] (lane's cur cols) and
    // h[CPL] (horizontal 5-tap at the lane's down cols).
    auto proc_row = [&](int s, float* c, float* h) {
        const char* pa = ring + (s & 3) * SLOT;
        if constexpr (CPL == 4) {
            float4 x0 = *(const float4*)(pa + 16 * lane);           // cols 4l..
            float4 x1 = *(const float4*)(pa + 1024 + 16 * lane);    // cols 256+4l..
            if constexpr (ISL0) {
                const char* pb = pa + ROWB;
                float4 y0 = *(const float4*)(pb + 16 * lane);
                float4 y1 = *(const float4*)(pb + 1024 + 16 * lane);
                x0.x -= y0.x; x0.y -= y0.y; x0.z -= y0.z; x0.w -= y0.w;
                x1.x -= y1.x; x1.y -= y1.y; x1.z -= y1.z; x1.w -= y1.w;
            }
            c[0]=x0.x; c[1]=x0.y; c[2]=x0.z; c[3]=x0.w;
            c[4]=x1.x; c[5]=x1.y; c[6]=x1.z; c[7]=x1.w;
            float lu2  = __shfl_up(x0.z, 1, 64);
            float lu3  = __shfl_up(x0.w, 1, 64);
            float rd0  = __shfl_down(x0.x, 1, 64);
            float bcA  = __shfl(x1.x, 0, 64);     // col 256 (half1 lane0)
            float lu2b = __shfl_up(x1.z, 1, 64);
            float lu3b = __shfl_up(x1.w, 1, 64);
            float rd0b = __shfl_down(x1.x, 1, 64);
            float bcZ  = __shfl(x0.z, 63, 64);    // col 254
            float bcW  = __shfl(x0.w, 63, 64);    // col 255
            float w0 = (lane == 0) ? x0.z : lu2;  // col 4l-2 (edge: col 2)
            float w1 = (lane == 0) ? x0.y : lu3;  // col 4l-1 (edge: col 1)
            float w6 = (lane == 63) ? bcA : rd0;  // col 4l+4 (boundary: 256)
            float v0 = (lane == 0) ? bcZ : lu2b;  // col 256+4l-2 (boundary: 254)
            float v1 = (lane == 0) ? bcW : lu3b;  // (boundary: 255)
            float v6 = (lane == 63) ? x1.z : rd0b; // col 256+4l+4 (edge: 510)
            h[0] = w0 + 4.f*w1 + 6.f*x0.x + 4.f*x0.y + x0.z;
            h[1] = x0.x + 4.f*x0.y + 6.f*x0.z + 4.f*x0.w + w6;
            h[2] = v0 + 4.f*v1 + 6.f*x1.x + 4.f*x1.y + x1.z;
            h[3] = x1.x + 4.f*x1.y + 6.f*x1.z + 4.f*x1.w + v6;
        } else if constexpr (CPL == 2) {
            float4 x0 = *(const float4*)(pa + 16 * lane);
            c[0]=x0.x; c[1]=x0.y; c[2]=x0.z; c[3]=x0.w;
            float lu2 = __shfl_up(x0.z, 1, 64);
            float lu3 = __shfl_up(x0.w, 1, 64);
            float rd0 = __shfl_down(x0.x, 1, 64);
            float w0 = (lane == 0) ? x0.z : lu2;
            float w1 = (lane == 0) ? x0.y : lu3;
            float w6 = (lane == 63) ? x0.z : rd0;  // col S -> S-2 reflect
            h[0] = w0 + 4.f*w1 + 6.f*x0.x + 4.f*x0.y + x0.z;
            h[1] = x0.x + 4.f*x0.y + 6.f*x0.z + 4.f*x0.w + w6;
        } else {
            float2 x0 = *(const float2*)(pa + 8 * lane);  // cols 2l, 2l+1
            c[0]=x0.x; c[1]=x0.y;
            float lu0 = __shfl_up(x0.x, 1, 64);
            float lu1 = __shfl_up(x0.y, 1, 64);
            float rd0 = __shfl_down(x0.x, 1, 64);
            float w0 = (lane == 0) ? rd0 : lu0;    // col 2l-2 (edge: col 2)
            float w1 = (lane == 0) ? x0.y : lu1;   // col 2l-1 (edge: col 1)
            float w4 = (lane == 63) ? x0.x : rd0;  // col 2l+2 (edge: S-2)
            h[0] = w0 + 4.f*w1 + 6.f*x0.x + 4.f*x0.y + w4;
        }
    };

    float hA[CPL], hB[CPL], hC[CPL], hD[CPL], hE[CPL];
    float cEv1[2*CPL], cEv2[2*CPL], cOd1[2*CPL], dump[2*CPL];
    float ex0[CPL] = {}, ex1[CPL] = {}, ox0[CPL] = {}, ox1[CPL] = {};
    float sum = 0.f;
    float* dbase = dwn + (size_t)n * D * D;

    // prologue: fill 4 slots, h for rows 0-2, refill freed slots with 4-6
    stage_row(0); stage_row(1); stage_row(2); stage_row(3);
    wait_vm<OPS>();                       // rows 0-2 landed (row 3 may fly)
    proc_row(0, dump, hA);
    proc_row(1, dump, hB);
    proc_row(2, dump, hC);
    LGKM0;
    stage_row(4); stage_row(5); stage_row(6);

    #pragma unroll
    for (int j = 0; j <= DH + 1; ++j) {
        const int m = R0 - 1 + j;
        if (j <= DH) wait_vm<2 * OPS>(); else wait_vm<0>();

        float c3[2*CPL], c4[2*CPL];
        proc_row(2 * j + 3, c3, hD);
        proc_row(2 * j + 4, c4, hE);

        float d[CPL], dl[CPL], dr[CPL], ex2[CPL], ox2[CPL];
        #pragma unroll
        for (int q = 0; q < CPL; q++)
            d[q] = (hA[q] + 4.f*hB[q] + 6.f*hC[q] + 4.f*hD[q] + hE[q]) * (1.f / 256.f);

        if constexpr (CPL == 4) {
            float su1 = __shfl_up(d[1], 1, 64);    // down col 2l-1
            float su3 = __shfl_up(d[3], 1, 64);    // down col 127+2l
            float sd0 = __shfl_down(d[0], 1, 64);  // down col 2l+2
            float sd2 = __shfl_down(d[2], 1, 64);  // down col 130+2l
            float bc1 = __shfl(d[1], 63, 64);      // down col 127
            float bc2 = __shfl(d[2], 0, 64);       // down col 128
            dl[0] = (lane == 0) ? d[1] : su1;      // col -1 -> 1
            dl[1] = d[0];
            dl[2] = (lane == 0) ? bc1 : su3;
            dl[3] = d[2];
            dr[0] = d[1];
            dr[1] = (lane == 63) ? bc2 : sd0;
            dr[2] = d[3];
            dr[3] = (lane == 63) ? d[3] : sd2;     // col D -> D-1
        } else if constexpr (CPL == 2) {
            float su1 = __shfl_up(d[1], 1, 64);
            float sd0 = __shfl_down(d[0], 1, 64);
            dl[0] = (lane == 0) ? d[1] : su1;
            dl[1] = d[0];
            dr[0] = d[1];
            dr[1] = (lane == 63) ? d[1] : sd0;
        } else {
            float su = __shfl_up(d[0], 1, 64);
            float sd = __shfl_down(d[0], 1, 64);
            dl[0] = (lane == 0) ? sd : su;
            dr[0] = (lane == 63) ? d[0] : sd;
        }
        #pragma unroll
        for (int q = 0; q < CPL; q++) {
            ex2[q] = 0.125f * (dl[q] + 6.f * d[q] + dr[q]);
            ox2[q] = 0.5f * (d[q] + dr[q]);
        }

        if (j >= 1 && j <= DH) {
            if constexpr (CPL == 4) {
                *(float2*)(dbase + (size_t)m * D + 2 * lane) = make_float2(d[0], d[1]);
                *(float2*)(dbase + (size_t)m * D + D / 2 + 2 * lane) = make_float2(d[2], d[3]);
            } else if constexpr (CPL == 2) {
                *(float2*)(dbase + (size_t)m * D + 2 * lane) = make_float2(d[0], d[1]);
            } else {
                dbase[(size_t)m * D + lane] = d[0];
            }
        }

        if (j >= 2) {
            const int me = m - 1;
            #pragma unroll
            for (int q = 0; q < CPL; q++) {
                float eA = (me == 0) ? ex2[q] : ex0[q];       // down row -1 -> 1
                float oA = (me == 0) ? ox2[q] : ox0[q];
                float eC = (me == D - 1) ? ex1[q] : ex2[q];   // down row D -> D-1
                float oC = (me == D - 1) ? ox1[q] : ox2[q];
                float uee = 0.125f * (eA + 6.f * ex1[q] + eC);
                float ueo = 0.125f * (oA + 6.f * ox1[q] + oC);
                float uoe = 0.5f * (ex1[q] + eC);
                float uoo = 0.5f * (ox1[q] + oC);
                sum += fabsf(cEv2[2*q]   - uee) + fabsf(cEv2[2*q+1] - ueo)
                     + fabsf(cOd1[2*q]   - uoe) + fabsf(cOd1[2*q+1] - uoo);
            }
        }

        #pragma unroll
        for (int q = 0; q < CPL; q++) {
            ex0[q] = ex1[q]; ex1[q] = ex2[q];
            ox0[q] = ox1[q]; ox1[q] = ox2[q];
            hA[q] = hC[q]; hB[q] = hD[q]; hC[q] = hE[q];
        }
        #pragma unroll
        for (int q = 0; q < 2 * CPL; q++) {
            cEv2[q] = cEv1[q];          // cur row seq 2j (even lap row)
            cEv1[q] = c4[q];            // seq 2j+4 -> lap @ j+2
            cOd1[q] = c3[q];            // seq 2j+3 -> lap @ j+1
        }

        if (j <= DH - 1) {
            LGKM0;                      // ds_reads retired before slot reuse
            stage_row(2 * j + 7);
            stage_row(2 * j + 8);
        }
    }

    #pragma unroll
    for (int o = 32; o > 0; o >>= 1) sum += __shfl_down(sum, o, 64);
    if (lane == 0) atomicAdd(&acc[wid & 63], sum * scale);
}

// ---- tail: levels 3+4 per image in LDS (proven R8-R10) ----
__device__ float level_in_lds(const float* cur, float* h, float* dn,
                              int S, int tid, int nt) {
    const int D = S >> 1;
    for (int i = tid; i < S * D; i += nt) {
        int r = i / D, xh = i % D;
        int c0 = reflect_i(2 * xh - 2, S), c1 = reflect_i(2 * xh - 1, S);
        int c3 = 2 * xh + 1, c4 = reflect_i(2 * xh + 2, S);
        const float* row = cur + r * S;
        h[i] = row[c0] + 4.f * row[c1] + 6.f * row[2 * xh] + 4.f * row[c3] + row[c4];
    }
    wg_barrier();
    for (int i = tid; i < D * D; i += nt) {
        int yh = i / D, xh = i % D;
        int r0 = reflect_i(2 * yh - 2, S), r1 = reflect_i(2 * yh - 1, S);
        int r3 = 2 * yh + 1, r4 = reflect_i(2 * yh + 2, S);
        dn[i] = (h[r0 * D + xh] + 4.f * h[r1 * D + xh] + 6.f * h[2 * yh * D + xh]
               + 4.f * h[r3 * D + xh] + h[r4 * D + xh]) * (1.f / 256.f);
    }
    wg_barrier();
    float sum = 0.f;
    for (int i = tid; i < D * D; i += nt) {
        int yh2 = i / D, q = i % D;
        int rm = (yh2 == 0) ? 1 : yh2 - 1;
        int rp = (yh2 == D - 1) ? D - 1 : yh2 + 1;
        int cm = (q == 0) ? 1 : q - 1;
        int cp = (q == D - 1) ? D - 1 : q + 1;
        float A00 = dn[rm * D + cm], A01 = dn[rm * D + q], A02 = dn[rm * D + cp];
        float A10 = dn[yh2 * D + cm], A11 = dn[yh2 * D + q], A12 = dn[yh2 * D + cp];
        float A20 = dn[rp * D + cm], A21 = dn[rp * D + q], A22 = dn[rp * D + cp];
        float ex0 = (A00 + 6.f * A01 + A02) * 0.125f;
        float ex1 = (A10 + 6.f * A11 + A12) * 0.125f;
        float ex2 = (A20 + 6.f * A21 + A22) * 0.125f;
        float ox0 = (A01 + A02) * 0.5f;
        float ox1 = (A11 + A12) * 0.5f;
        float ox2 = (A21 + A22) * 0.5f;
        float uee = (ex0 + 6.f * ex1 + ex2) * 0.125f;
        float ueo = (ox0 + 6.f * ox1 + ox2) * 0.125f;
        float uoe = (ex1 + ex2) * 0.5f;
        float uoo = (ox1 + ox2) * 0.5f;
        const float* c0 = cur + (2 * yh2) * S + 2 * q;
        sum += fabsf(c0[0] - uee) + fabsf(c0[1] - ueo)
             + fabsf(c0[S] - uoe) + fabsf(c0[S + 1] - uoo);
    }
    wg_barrier();
    return sum;
}

__global__ __launch_bounds__(256)
void tail_kernel(const float* __restrict__ d2, float* __restrict__ acc,
                 float s3, float s4) {
    __shared__ float cur[64 * 64];
    __shared__ float hbuf[64 * 32];
    __shared__ float dn3[32 * 32];
    __shared__ float dn4[16 * 16];
    int n = blockIdx.x, tid = threadIdx.x;
    const float4* src = (const float4*)(d2 + (size_t)n * 64 * 64);
    for (int i = tid; i < 64 * 16; i += 256) ((float4*)cur)[i] = src[i];
    wg_barrier();
    float sum = level_in_lds(cur, hbuf, dn3, 64, tid, 256) * s3;
    sum += level_in_lds(dn3, hbuf, dn4, 32, tid, 256) * s4;
    #pragma unroll
    for (int o = 32; o > 0; o >>= 1) sum += __shfl_down(sum, o, 64);
    __shared__ float s[4];
    int lane = tid & 63, w = tid >> 6;
    if (lane == 0) s[w] = sum;
    wg_barrier();
    if (tid == 0) atomicAdd(&acc[n & 63], s[0] + s[1] + s[2] + s[3]);
}

__global__ void finish_kernel(const float* __restrict__ acc, float* __restrict__ out) {
    float v = acc[threadIdx.x];
    #pragma unroll
    for (int o = 32; o > 0; o >>= 1) v += __shfl_down(v, o, 64);
    if (threadIdx.x == 0) out[0] = v;
}

extern "C" void kernel_launch(void* const* d_in, const int* in_sizes, int n_in,
                              void* d_out, int out_size, void* d_ws, size_t ws_size,
                              hipStream_t stream) {
    const float* p = (const float*)d_in[0];
    const float* t = (const float*)d_in[1];
    float* out = (float*)d_out;
    float* acc = (float*)d_ws;                    // 64 accumulator slots
    float* dn0 = acc + 64;                        // 48 * 256 * 256
    float* dn1 = dn0 + (size_t)48 * 256 * 256;    // 48 * 128 * 128
    float* dn2 = dn1 + (size_t)48 * 128 * 128;    // 48 * 64 * 64

    hipMemsetAsync(acc, 0, 64 * sizeof(float), stream);

    const int N = 48;  // 16 batch * 3 channels (depthwise)

    // L0: D=256, DH=8 -> 32 bands/img, 1536 waves in 384 blocks
    pyr_kernel<512, 1, 8><<<384, 256, 0, stream>>>(
        p, t, dn0, acc, 1.f / (float)(N * 512 * 512));
    // L1: D=128, DH=8 -> 16 bands/img, 768 waves in 192 blocks
    pyr_kernel<256, 0, 8><<<192, 256, 0, stream>>>(
        dn0, nullptr, dn1, acc, 2.f / (float)(N * 256 * 256));
    // L2: D=64, DH=8 -> 8 bands/img, 384 waves in 96 blocks
    pyr_kernel<128, 0, 8><<<96, 256, 0, stream>>>(
        dn1, nullptr, dn2, acc, 4.f / (float)(N * 128 * 128));
    // L3+L4: one block per image, LDS-resident
    tail_kernel<<<N, 256, 0, stream>>>(dn2, acc,
                                       8.f / (float)(N * 64 * 64),
                                       16.f / (float)(N * 32 * 32));
    finish_kernel<<<1, 64, 0, stream>>>(acc, out);
}